// Round 11
// baseline (184.803 us; speedup 1.0000x reference)
//
#include <hip/hip_runtime.h>

typedef __fp16 h2 __attribute__((ext_vector_type(2)));

constexpr int VIEWS = 360;
constexpr int IMGSZ = 512;
constexpr int WCHUNK = 64;   // w per block
constexpr int KH = 32;       // h per LDS chunk (small tile -> 6 blocks/CU)
constexpr int NXF4 = 20;     // staged box width in 4-dword groups (80 texels)
constexpr int PITCH = 80;    // dwords (texel positions) per LDS row
constexpr int MAXNY = 76;    // max staged rows: sqrt(63^2+31^2)+6 < 76
// tile = 6144 dwords = 24576 B -> 6 blocks/CU (24 waves, ~75% occupancy)

// Single fused kernel: each block stages its rotated bounding box directly
// from the two fp32 image planes (batch-packed f16 per dword), then gathers
// bilinear samples from LDS. One dispatch total.
__global__ __launch_bounds__(256) void fp_kernel(const float* __restrict__ x,
                                                 float* __restrict__ out) {
    __shared__ __align__(16) unsigned tileU[6144];

    int blk = blockIdx.x;          // 2880 = VIEWS * 8
    int wc = blk & 7;
    int v = blk >> 3;

    int tid = threadIdx.x;
    int lane = tid & 63;
    int g = tid >> 6;              // h phase 0..3
    int w = wc * WCHUNK + lane;

    double ang = -3.14159265358979323846 * (double)(v + 1) / (double)VIEWS
                 - 3.14159265358979323846;
    float c = (float)cos(ang);
    float s = (float)sin(ang);

    const float* __restrict__ img0 = x;
    const float* __restrict__ img1 = x + (size_t)IMGSZ * IMGSZ;

    float xw = (float)w + 0.5f - 256.0f;
    float cxw = fmaf(c, xw, 255.5f);
    float sxw = fmaf(s, xw, 255.5f);

    // Per-thread valid-h interval (identical to validated rounds 2-10).
    float lo = -1e30f, hi = 1e30f;
    {
        float coef = -s, base = cxw;
        if (fabsf(coef) > 1e-6f) {
            float a = (-1.0f - base) / coef;
            float bq = (512.0f - base) / coef;
            lo = fmaxf(lo, fminf(a, bq));
            hi = fminf(hi, fmaxf(a, bq));
        } else if (!(base > -1.0f && base < 512.0f)) {
            lo = 1e30f; hi = -1e30f;
        }
    }
    {
        float coef = c, base = sxw;
        if (fabsf(coef) > 1e-6f) {
            float a = (-1.0f - base) / coef;
            float bq = (512.0f - base) / coef;
            lo = fmaxf(lo, fminf(a, bq));
            hi = fminf(hi, fmaxf(a, bq));
        } else if (!(base > -1.0f && base < 512.0f)) {
            lo = 1e30f; hi = -1e30f;
        }
    }
    float h0f = fminf(fmaxf(floorf(lo + 255.5f) - 1.0f, 0.0f), 512.0f);
    float h1f = fminf(fmaxf(ceilf(hi + 255.5f) + 1.0f, -1.0f), 511.0f);
    int h0 = (int)h0f;
    int h1 = (int)h1f;

    int bh0 = h0, bh1 = h1;
    #pragma unroll
    for (int m = 1; m < 64; m <<= 1) {
        bh0 = min(bh0, __shfl_xor(bh0, m, 64));
        bh1 = max(bh1, __shfl_xor(bh1, m, 64));
    }

    float xa = (float)(wc * WCHUNK) + 0.5f - 256.0f;
    float xb = xa + 63.0f;

    float acc0 = 0.0f, acc1 = 0.0f;
    float step4x = -4.0f * s;
    float step4y = 4.0f * c;

    for (int hc = bh0; hc <= bh1; hc += KH) {
        int hend = min(hc + KH - 1, bh1);

        float ha = (float)hc - 255.5f;
        float hb = (float)hend - 255.5f;
        float ix00 = c * xa - s * ha, ix01 = c * xa - s * hb;
        float ix10 = c * xb - s * ha, ix11 = c * xb - s * hb;
        float iy00 = s * xa + c * ha, iy01 = s * xa + c * hb;
        float iy10 = s * xb + c * ha, iy11 = s * xb + c * hb;
        float ixmn = fminf(fminf(ix00, ix01), fminf(ix10, ix11)) + 255.5f;
        float iymn = fminf(fminf(iy00, iy01), fminf(iy10, iy11)) + 255.5f;
        float iymx = fmaxf(fmaxf(iy00, iy01), fmaxf(iy10, iy11)) + 255.5f;
        int x_lo = (int)floorf(ixmn) - 1;
        int x_lo4 = x_lo & ~3;
        int y_lo = (int)floorf(iymn) - 1;
        int NY = min((int)floorf(iymx) + 3 - y_lo, MAXNY);
        int total4 = NY * NXF4;
        int nit = (total4 + 255) >> 8;     // <= 6

        __syncthreads();

        // Fused staging: masked f32 loads from both planes, pack to
        // batch-paired f16 dwords. Group-of-4 cols are all-in/all-out
        // (x_lo4 multiple of 4), so one uniform bounds test per group.
        for (int k = 0; k < nit; ++k) {
            int i = (k << 8) + tid;
            int ic = min(i, total4 - 1);
            int ry = ic / NXF4;                       // magic-mul (const 20)
            int rx4 = ic - ry * NXF4;
            int gy = y_lo + ry;
            int gx = x_lo4 + (rx4 << 2);
            bool ok = ((unsigned)gy < (unsigned)IMGSZ) &
                      ((unsigned)gx < (unsigned)IMGSZ);
            float4 a = make_float4(0.f, 0.f, 0.f, 0.f);
            float4 bq = a;
            if (ok) {
                size_t off = (size_t)gy * IMGSZ + gx;
                a  = *(const float4*)(img0 + off);
                bq = *(const float4*)(img1 + off);
            }
            uint4 d;
            d.x = __builtin_bit_cast(unsigned, __builtin_amdgcn_cvt_pkrtz(a.x, bq.x));
            d.y = __builtin_bit_cast(unsigned, __builtin_amdgcn_cvt_pkrtz(a.y, bq.y));
            d.z = __builtin_bit_cast(unsigned, __builtin_amdgcn_cvt_pkrtz(a.z, bq.z));
            d.w = __builtin_bit_cast(unsigned, __builtin_amdgcn_cvt_pkrtz(a.w, bq.w));
            *(uint4*)&tileU[i << 2] = d;
        }
        __syncthreads();

        // Gather: 2 x ds_read2_b32 per sample; packed-f16 lerp serves both
        // batches at once. Wave g handles h = hc+g, +4, ...
        float hh0 = (float)(hc + g) - 255.5f;
        float ixr = fmaf(-s, hh0, cxw) - (float)x_lo4;
        float iyr = fmaf(c, hh0, sxw) - (float)y_lo;
        h2 accp0 = (h2)0.0f;
        h2 accp1 = (h2)0.0f;
        int parity = 0;
        #pragma unroll 4
        for (int h = hc + g; h <= hend; h += 4) {
            float fx = floorf(ixr);
            float fy = floorf(iyr);
            int lx = (int)fx;
            int ly = (int)fy;
            float wx1 = ixr - fx;
            float wy1 = iyr - fy;
            h2 wxs = __builtin_amdgcn_cvt_pkrtz(wx1, wx1);
            h2 wys = __builtin_amdgcn_cvt_pkrtz(wy1, wy1);
            const unsigned* p = tileU + (ly * PITCH + lx);
            h2 t00 = __builtin_bit_cast(h2, p[0]);
            h2 t01 = __builtin_bit_cast(h2, p[1]);
            h2 t10 = __builtin_bit_cast(h2, p[PITCH]);
            h2 t11 = __builtin_bit_cast(h2, p[PITCH + 1]);
            h2 r0 = t00 + (t01 - t00) * wxs;
            h2 r1 = t10 + (t11 - t10) * wxs;
            h2 contrib = r0 + (r1 - r0) * wys;
            if (parity) accp1 += contrib; else accp0 += contrib;
            parity ^= 1;
            ixr += step4x;
            iyr += step4y;
        }
        acc0 += (float)accp0.x + (float)accp1.x;
        acc1 += (float)accp0.y + (float)accp1.y;
    }

    // Reduce the 4 h-phase partials for both batches, reusing the tile.
    __syncthreads();
    tileU[(g << 6) + lane] = __float_as_uint(acc0);
    tileU[256 + (g << 6) + lane] = __float_as_uint(acc1);
    __syncthreads();
    if (g == 0) {
        float r0 = __uint_as_float(tileU[lane]) + __uint_as_float(tileU[64 + lane]) +
                   __uint_as_float(tileU[128 + lane]) + __uint_as_float(tileU[192 + lane]);
        float r1 = __uint_as_float(tileU[256 + lane]) + __uint_as_float(tileU[320 + lane]) +
                   __uint_as_float(tileU[384 + lane]) + __uint_as_float(tileU[448 + lane]);
        size_t o = (size_t)w * VIEWS + v;
        out[o] = r0 * 0.5f;
        out[(size_t)IMGSZ * VIEWS + o] = r1 * 0.5f;
    }
}

extern "C" void kernel_launch(void* const* d_in, const int* in_sizes, int n_in,
                              void* d_out, int out_size, void* d_ws, size_t ws_size,
                              hipStream_t stream) {
    const float* x = (const float*)d_in[0];
    float* out = (float*)d_out;
    int nblocks = VIEWS * (IMGSZ / WCHUNK);          // 2880
    fp_kernel<<<nblocks, 256, 0, stream>>>(x, out);
}

// Round 12
// 153.667 us; speedup vs baseline: 1.2026x; 1.2026x over previous
//
#include <hip/hip_runtime.h>

typedef __fp16 h2 __attribute__((ext_vector_type(2)));

constexpr int VIEWS = 360;
constexpr int IMGSZ = 512;
constexpr int WCHUNK = 64;   // w per block
constexpr int KH = 64;       // h per LDS chunk
constexpr int NXF4 = 25;     // staged box width in 4-dword groups (100 texels)
constexpr int PITCH = 100;   // dwords (texel positions) per LDS row
constexpr int MAXNY = 94;    // max staged rows
constexpr int PW = 712;      // padded width (dword positions per row)
constexpr int PH = 704;      // padded height
constexpr int PAD = 96;

// ---------- pad kernel: zero-padded, BATCH-PACKED f16 texels ---------------
// padq[py][px] = (f16 img_b0[py-PAD][px-PAD], f16 img_b1[py-PAD][px-PAD])
__global__ __launch_bounds__(256) void pad_kernel(const float* __restrict__ x,
                                                  unsigned* __restrict__ padq) {
    constexpr int PW4 = PW / 4;              // 178 groups per row
    constexpr int total = PH * PW4;          // 125312 groups
    int idx = blockIdx.x * 256 + threadIdx.x;
    if (idx >= total) return;
    int py = idx / PW4;
    int px4 = idx - py * PW4;
    int gx = px4 * 4 - PAD;                  // multiple of 4
    int gy = py - PAD;
    const float* img0 = x;
    const float* img1 = x + (size_t)IMGSZ * IMGSZ;
    float4 a = make_float4(0.f, 0.f, 0.f, 0.f);
    float4 bq = a;
    if ((unsigned)gy < (unsigned)IMGSZ && (unsigned)gx < (unsigned)IMGSZ) {
        size_t off = (size_t)gy * IMGSZ + gx;    // gx%4==0 -> all-in/all-out
        a  = *(const float4*)(img0 + off);
        bq = *(const float4*)(img1 + off);
    }
    uint4 d;
    d.x = __builtin_bit_cast(unsigned, __builtin_amdgcn_cvt_pkrtz(a.x, bq.x));
    d.y = __builtin_bit_cast(unsigned, __builtin_amdgcn_cvt_pkrtz(a.y, bq.y));
    d.z = __builtin_bit_cast(unsigned, __builtin_amdgcn_cvt_pkrtz(a.z, bq.z));
    d.w = __builtin_bit_cast(unsigned, __builtin_amdgcn_cvt_pkrtz(a.w, bq.w));
    *(uint4*)&padq[(size_t)idx * 4] = d;
}

// ---------- main kernel: copy-only staging, packed-f16 lerp gather ---------
__global__ __launch_bounds__(256) void fp_kernel(const unsigned* __restrict__ padq,
                                                 float* __restrict__ out) {
    // Exactly the needed footprint: 25*4 x 94 = 9400 dwords = 37600 B
    // -> 4 blocks/CU (vs r10's 10240-dword tile -> 3 blocks/CU).
    __shared__ __align__(16) unsigned tileU[PITCH * MAXNY];

    int blk = blockIdx.x;          // 2880 = VIEWS * 8
    int wc = blk & 7;
    int v = blk >> 3;

    int tid = threadIdx.x;
    int lane = tid & 63;
    int g = tid >> 6;              // h phase 0..3
    int w = wc * WCHUNK + lane;

    double ang = -3.14159265358979323846 * (double)(v + 1) / (double)VIEWS
                 - 3.14159265358979323846;
    float c = (float)cos(ang);
    float s = (float)sin(ang);

    float xw = (float)w + 0.5f - 256.0f;
    float cxw = fmaf(c, xw, 255.5f);
    float sxw = fmaf(s, xw, 255.5f);

    // Per-thread valid-h interval (identical to validated rounds 2-11).
    float lo = -1e30f, hi = 1e30f;
    {
        float coef = -s, base = cxw;
        if (fabsf(coef) > 1e-6f) {
            float a = (-1.0f - base) / coef;
            float bq = (512.0f - base) / coef;
            lo = fmaxf(lo, fminf(a, bq));
            hi = fminf(hi, fmaxf(a, bq));
        } else if (!(base > -1.0f && base < 512.0f)) {
            lo = 1e30f; hi = -1e30f;
        }
    }
    {
        float coef = c, base = sxw;
        if (fabsf(coef) > 1e-6f) {
            float a = (-1.0f - base) / coef;
            float bq = (512.0f - base) / coef;
            lo = fmaxf(lo, fminf(a, bq));
            hi = fminf(hi, fmaxf(a, bq));
        } else if (!(base > -1.0f && base < 512.0f)) {
            lo = 1e30f; hi = -1e30f;
        }
    }
    float h0f = fminf(fmaxf(floorf(lo + 255.5f) - 1.0f, 0.0f), 512.0f);
    float h1f = fminf(fmaxf(ceilf(hi + 255.5f) + 1.0f, -1.0f), 511.0f);
    int h0 = (int)h0f;
    int h1 = (int)h1f;

    int bh0 = h0, bh1 = h1;
    #pragma unroll
    for (int m = 1; m < 64; m <<= 1) {
        bh0 = min(bh0, __shfl_xor(bh0, m, 64));
        bh1 = max(bh1, __shfl_xor(bh1, m, 64));
    }

    float xa = (float)(wc * WCHUNK) + 0.5f - 256.0f;
    float xb = xa + 63.0f;

    float acc0 = 0.0f, acc1 = 0.0f;
    float step4x = -4.0f * s;
    float step4y = 4.0f * c;

    for (int hc = bh0; hc <= bh1; hc += KH) {
        int hend = min(hc + KH - 1, bh1);

        float ha = (float)hc - 255.5f;
        float hb = (float)hend - 255.5f;
        float ix00 = c * xa - s * ha, ix01 = c * xa - s * hb;
        float ix10 = c * xb - s * ha, ix11 = c * xb - s * hb;
        float iy00 = s * xa + c * ha, iy01 = s * xa + c * hb;
        float iy10 = s * xb + c * ha, iy11 = s * xb + c * hb;
        float ixmn = fminf(fminf(ix00, ix01), fminf(ix10, ix11)) + 255.5f;
        float iymn = fminf(fminf(iy00, iy01), fminf(iy10, iy11)) + 255.5f;
        float iymx = fmaxf(fmaxf(iy00, iy01), fmaxf(iy10, iy11)) + 255.5f;
        int x_lo = (int)floorf(ixmn) - 1;
        int x_lo4 = x_lo & ~3;
        int y_lo = (int)floorf(iymn) - 1;
        int NY = min((int)floorf(iymx) + 3 - y_lo, MAXNY);
        int total4 = NY * NXF4;
        int nit = (total4 + 255) >> 8;     // <= 10

        __syncthreads();

        // Copy-only staging of batch-packed texels; clamped slot index for
        // BOTH load and store (duplicate same-value LDS writes are benign)
        // keeps the tile at its true 9400-dword footprint.
        {
            const unsigned* pb = padq + (y_lo + PAD) * PW + (x_lo4 + PAD);
            for (int k = 0; k < nit; ++k) {
                int i = (k << 8) + tid;
                int ic = min(i, total4 - 1);
                int ry = ic / NXF4;                    // magic-mul (const 25)
                uint4 val = *(const uint4*)(pb + 4 * ic + (PW - 4 * NXF4) * ry);
                *(uint4*)&tileU[ic << 2] = val;
            }
        }
        __syncthreads();

        // Gather: 2 x ds_read2_b32 per sample; packed-f16 lerp serves both
        // batches at once. Wave g handles h = hc+g, +4, ...
        float hh0 = (float)(hc + g) - 255.5f;
        float ixr = fmaf(-s, hh0, cxw) - (float)x_lo4;
        float iyr = fmaf(c, hh0, sxw) - (float)y_lo;
        h2 accp0 = (h2)0.0f;
        h2 accp1 = (h2)0.0f;
        int parity = 0;
        #pragma unroll 4
        for (int h = hc + g; h <= hend; h += 4) {
            float fx = floorf(ixr);
            float fy = floorf(iyr);
            int lx = (int)fx;
            int ly = (int)fy;
            float wx1 = ixr - fx;
            float wy1 = iyr - fy;
            h2 wxs = __builtin_amdgcn_cvt_pkrtz(wx1, wx1);
            h2 wys = __builtin_amdgcn_cvt_pkrtz(wy1, wy1);
            const unsigned* p = tileU + (ly * PITCH + lx);
            h2 t00 = __builtin_bit_cast(h2, p[0]);
            h2 t01 = __builtin_bit_cast(h2, p[1]);
            h2 t10 = __builtin_bit_cast(h2, p[PITCH]);
            h2 t11 = __builtin_bit_cast(h2, p[PITCH + 1]);
            h2 r0 = t00 + (t01 - t00) * wxs;
            h2 r1 = t10 + (t11 - t10) * wxs;
            h2 contrib = r0 + (r1 - r0) * wys;
            if (parity) accp1 += contrib; else accp0 += contrib;
            parity ^= 1;
            ixr += step4x;
            iyr += step4y;
        }
        acc0 += (float)accp0.x + (float)accp1.x;
        acc1 += (float)accp0.y + (float)accp1.y;
    }

    // Reduce the 4 h-phase partials for both batches, reusing the tile.
    __syncthreads();
    tileU[(g << 6) + lane] = __float_as_uint(acc0);
    tileU[256 + (g << 6) + lane] = __float_as_uint(acc1);
    __syncthreads();
    if (g == 0) {
        float r0 = __uint_as_float(tileU[lane]) + __uint_as_float(tileU[64 + lane]) +
                   __uint_as_float(tileU[128 + lane]) + __uint_as_float(tileU[192 + lane]);
        float r1 = __uint_as_float(tileU[256 + lane]) + __uint_as_float(tileU[320 + lane]) +
                   __uint_as_float(tileU[384 + lane]) + __uint_as_float(tileU[448 + lane]);
        size_t o = (size_t)w * VIEWS + v;
        out[o] = r0 * 0.5f;
        out[(size_t)IMGSZ * VIEWS + o] = r1 * 0.5f;
    }
}

extern "C" void kernel_launch(void* const* d_in, const int* in_sizes, int n_in,
                              void* d_out, int out_size, void* d_ws, size_t ws_size,
                              hipStream_t stream) {
    const float* x = (const float*)d_in[0];
    float* out = (float*)d_out;
    unsigned* padq = (unsigned*)d_ws;   // PH*PW*4 = 2,004,992 bytes

    constexpr int padTotal = PH * (PW / 4);          // 125312 groups
    pad_kernel<<<(padTotal + 255) / 256, 256, 0, stream>>>(x, padq);

    int nblocks = VIEWS * (IMGSZ / WCHUNK);          // 2880
    fp_kernel<<<nblocks, 256, 0, stream>>>(padq, out);
}